// Round 1
// baseline (3310.114 us; speedup 1.0000x reference)
//
#include <hip/hip_runtime.h>

#define D 64
#define NREL 3

// hr[r][n][od] = sum_k x[n][k] * W[r][k][od], for r = 0..2
__global__ __launch_bounds__(256) void transform_kernel(
    const float* __restrict__ x, const float* __restrict__ W,
    float* __restrict__ hr, int n_nodes) {
  __shared__ float xs[64 * 64];        // 16 KB
  __shared__ float wl[NREL * 64 * 64]; // 48 KB
  const int tid = threadIdx.x;
  const int base = blockIdx.x * 64;

  for (int idx = tid; idx < NREL * 64 * 64; idx += 256) wl[idx] = W[idx];
  const int nrows = min(64, n_nodes - base);
  for (int idx = tid; idx < nrows * 64; idx += 256) xs[idx] = x[(long)base * 64 + idx];
  __syncthreads();

  const int od = tid & 63;
  const int ng = tid >> 6;
  for (int n = ng; n < nrows; n += 4) {
    const float* xrow = &xs[n * 64];
    float acc0 = 0.f, acc1 = 0.f, acc2 = 0.f;
#pragma unroll
    for (int k = 0; k < 64; ++k) {
      const float xv = xrow[k];  // same address across all 64 lanes -> LDS broadcast
      acc0 += xv * wl[0 * 4096 + k * 64 + od];
      acc1 += xv * wl[1 * 4096 + k * 64 + od];
      acc2 += xv * wl[2 * 4096 + k * 64 + od];
    }
    const long node = base + n;
    hr[(0L * n_nodes + node) * 64 + od] = acc0;
    hr[(1L * n_nodes + node) * 64 + od] = acc1;
    hr[(2L * n_nodes + node) * 64 + od] = acc2;
  }
}

// 16 threads per edge, each handles one float4 chunk of the 64-wide message.
__global__ __launch_bounds__(256) void scatter_kernel(
    const float* __restrict__ hr, const int* __restrict__ src,
    const int* __restrict__ dst, const int* __restrict__ rel,
    const float* __restrict__ norm, float* __restrict__ agg,
    int n_nodes, int n_edges) {
  const long gid = (long)blockIdx.x * 256 + threadIdx.x;
  const long e = gid >> 4;
  if (e >= n_edges) return;
  const int c = (int)(gid & 15) * 4;

  const int r = rel[e];
  const int s = src[e];
  const int d = dst[e];
  const float nv = norm[e];

  const float4 v = *reinterpret_cast<const float4*>(
      &hr[((long)r * n_nodes + s) * 64 + c]);
  float* ap = &agg[(long)d * 64 + c];
  unsafeAtomicAdd(ap + 0, v.x * nv);
  unsafeAtomicAdd(ap + 1, v.y * nv);
  unsafeAtomicAdd(ap + 2, v.z * nv);
  unsafeAtomicAdd(ap + 3, v.w * nv);
}

// out = relu(agg [+ skip]), elementwise float4
__global__ __launch_bounds__(256) void relu_kernel(
    const float* __restrict__ agg, const float* __restrict__ skip,
    float* __restrict__ out, int n /* elements, multiple of 4 */) {
  const int i = blockIdx.x * 256 + threadIdx.x;  // float4 index
  if (i * 4 >= n) return;
  float4 a = reinterpret_cast<const float4*>(agg)[i];
  if (skip != nullptr) {
    const float4 s = reinterpret_cast<const float4*>(skip)[i];
    a.x += s.x; a.y += s.y; a.z += s.z; a.w += s.w;
  }
  a.x = fmaxf(a.x, 0.f);
  a.y = fmaxf(a.y, 0.f);
  a.z = fmaxf(a.z, 0.f);
  a.w = fmaxf(a.w, 0.f);
  reinterpret_cast<float4*>(out)[i] = a;
}

// xa = x@Wa.T + ba -> out[0 : N*2], xb = x@Wb.T + bb -> out[N*2 : N*2+N*21]
__global__ __launch_bounds__(256) void heads_kernel(
    const float* __restrict__ x, const float* __restrict__ Wa,
    const float* __restrict__ ba, const float* __restrict__ Wb,
    const float* __restrict__ bb, float* __restrict__ out, int n_nodes) {
  __shared__ float xs[64][65];
  __shared__ float wl[23][64];
  __shared__ float bl[23];
  const int tid = threadIdx.x;
  const int base = blockIdx.x * 64;

  for (int idx = tid; idx < 2 * 64; idx += 256) wl[idx >> 6][idx & 63] = Wa[idx];
  for (int idx = tid; idx < 21 * 64; idx += 256) wl[2 + (idx >> 6)][idx & 63] = Wb[idx];
  if (tid < 2) bl[tid] = ba[tid];
  else if (tid < 23) bl[tid] = bb[tid - 2];
  const int nrows = min(64, n_nodes - base);
  for (int idx = tid; idx < nrows * 64; idx += 256)
    xs[idx >> 6][idx & 63] = x[(long)base * 64 + idx];
  __syncthreads();

  for (int idx = tid; idx < nrows * 23; idx += 256) {
    const int n = idx / 23;
    const int s = idx % 23;
    float acc = 0.f;
#pragma unroll
    for (int k = 0; k < 64; ++k) acc += xs[n][k] * wl[s][k];
    acc += bl[s];
    const long node = base + n;
    if (s < 2) out[node * 2 + s] = acc;
    else out[(long)n_nodes * 2 + node * 21 + (s - 2)] = acc;
  }
}

extern "C" void kernel_launch(void* const* d_in, const int* in_sizes, int n_in,
                              void* d_out, int out_size, void* d_ws, size_t ws_size,
                              hipStream_t stream) {
  const float* v    = (const float*)d_in[0];
  const int*   esrc = (const int*)d_in[1];
  const int*   edst = (const int*)d_in[2];
  const int*   erel = (const int*)d_in[3];
  const float* norm = (const float*)d_in[4];
  const float* W1   = (const float*)d_in[5];
  const float* W2   = (const float*)d_in[6];
  const float* W3   = (const float*)d_in[7];
  const float* Wa   = (const float*)d_in[8];
  const float* ba   = (const float*)d_in[9];
  const float* Wb   = (const float*)d_in[10];
  const float* bb   = (const float*)d_in[11];

  const int nN = in_sizes[0] / D;   // 100000
  const int E  = in_sizes[1];      // 1200000

  float* hr   = (float*)d_ws;                  // [3][nN][64]
  float* bufA = hr + 3L * nN * D;              // [nN][64]
  float* bufB = bufA + (long)nN * D;           // [nN][64]
  const size_t node_bytes = (size_t)nN * D * sizeof(float);

  const int tblocks  = (nN + 63) / 64;
  const int scblocks = (int)(((long)E * 16 + 255) / 256);
  const int rlblocks = (nN * D / 4 + 255) / 256;

  // ---- layer 1: x = v -> bufA (no skip)
  transform_kernel<<<tblocks, 256, 0, stream>>>(v, W1, hr, nN);
  hipMemsetAsync(bufA, 0, node_bytes, stream);
  scatter_kernel<<<scblocks, 256, 0, stream>>>(hr, esrc, edst, erel, norm, bufA, nN, E);
  relu_kernel<<<rlblocks, 256, 0, stream>>>(bufA, nullptr, bufA, nN * D);

  // ---- layer 2: x = bufA -> bufB (skip)
  transform_kernel<<<tblocks, 256, 0, stream>>>(bufA, W2, hr, nN);
  hipMemsetAsync(bufB, 0, node_bytes, stream);
  scatter_kernel<<<scblocks, 256, 0, stream>>>(hr, esrc, edst, erel, norm, bufB, nN, E);
  relu_kernel<<<rlblocks, 256, 0, stream>>>(bufB, bufA, bufB, nN * D);

  // ---- layer 3: x = bufB -> bufA (skip)
  transform_kernel<<<tblocks, 256, 0, stream>>>(bufB, W3, hr, nN);
  hipMemsetAsync(bufA, 0, node_bytes, stream);
  scatter_kernel<<<scblocks, 256, 0, stream>>>(hr, esrc, edst, erel, norm, bufA, nN, E);
  relu_kernel<<<rlblocks, 256, 0, stream>>>(bufA, bufB, bufA, nN * D);

  // ---- heads
  heads_kernel<<<tblocks, 256, 0, stream>>>(bufA, Wa, ba, Wb, bb, (float*)d_out, nN);
}

// Round 3
// 505.698 us; speedup vs baseline: 6.5456x; 6.5456x over previous
//
#include <hip/hip_runtime.h>

#define D 64
#define NREL 3
#define SRC_MASK 0x07FFFFFF

// hr[r][n][od] = sum_k x[n][k] * W[r][k][od], for r = 0..2
__global__ __launch_bounds__(256) void transform_kernel(
    const float* __restrict__ x, const float* __restrict__ W,
    float* __restrict__ hr, int n_nodes) {
  __shared__ float xs[64 * 64];        // 16 KB
  __shared__ float wl[NREL * 64 * 64]; // 48 KB
  const int tid = threadIdx.x;
  const int base = blockIdx.x * 64;

  for (int idx = tid; idx < NREL * 64 * 64; idx += 256) wl[idx] = W[idx];
  const int nrows = min(64, n_nodes - base);
  for (int idx = tid; idx < nrows * 64; idx += 256) xs[idx] = x[(long)base * 64 + idx];
  __syncthreads();

  const int od = tid & 63;
  const int ng = tid >> 6;
  for (int n = ng; n < nrows; n += 4) {
    const float* xrow = &xs[n * 64];
    float acc0 = 0.f, acc1 = 0.f, acc2 = 0.f;
#pragma unroll
    for (int k = 0; k < 64; ++k) {
      const float xv = xrow[k];  // LDS broadcast
      acc0 += xv * wl[0 * 4096 + k * 64 + od];
      acc1 += xv * wl[1 * 4096 + k * 64 + od];
      acc2 += xv * wl[2 * 4096 + k * 64 + od];
    }
    const long node = base + n;
    hr[(0L * n_nodes + node) * 64 + od] = acc0;
    hr[(1L * n_nodes + node) * 64 + od] = acc1;
    hr[(2L * n_nodes + node) * 64 + od] = acc2;
  }
}

// ---------------- CSR build ----------------
__global__ __launch_bounds__(256) void hist_kernel(
    const int* __restrict__ dst, int* __restrict__ deg, int n_edges) {
  const int e = blockIdx.x * 256 + threadIdx.x;
  if (e < n_edges) atomicAdd(&deg[dst[e]], 1);
}

// Per-1024-chunk exclusive scan; partials[b] = chunk total.
__global__ __launch_bounds__(256) void scan1_kernel(
    const int* __restrict__ deg, int* __restrict__ offs,
    int* __restrict__ partials, int n_nodes) {
  __shared__ int ssum[256];
  const int t = threadIdx.x;
  const int base = blockIdx.x * 1024 + t * 4;
  int v0 = (base + 0 < n_nodes) ? deg[base + 0] : 0;
  int v1 = (base + 1 < n_nodes) ? deg[base + 1] : 0;
  int v2 = (base + 2 < n_nodes) ? deg[base + 2] : 0;
  int v3 = (base + 3 < n_nodes) ? deg[base + 3] : 0;
  const int lsum = v0 + v1 + v2 + v3;
  ssum[t] = lsum;
  __syncthreads();
  for (int off = 1; off < 256; off <<= 1) {
    const int add = (t >= off) ? ssum[t - off] : 0;
    __syncthreads();
    ssum[t] += add;
    __syncthreads();
  }
  const int excl = ssum[t] - lsum;
  if (base + 0 < n_nodes) offs[base + 0] = excl;
  if (base + 1 < n_nodes) offs[base + 1] = excl + v0;
  if (base + 2 < n_nodes) offs[base + 2] = excl + v0 + v1;
  if (base + 3 < n_nodes) offs[base + 3] = excl + v0 + v1 + v2;
  if (t == 255) partials[blockIdx.x] = ssum[255];
}

// Single block: exclusive scan of partials[n_chunks] in place (n_chunks <= 256).
__global__ __launch_bounds__(256) void scan2_kernel(int* __restrict__ partials,
                                                    int n_chunks) {
  __shared__ int s[256];
  const int t = threadIdx.x;
  const int v = (t < n_chunks) ? partials[t] : 0;
  s[t] = v;
  __syncthreads();
  for (int off = 1; off < 256; off <<= 1) {
    const int add = (t >= off) ? s[t - off] : 0;
    __syncthreads();
    s[t] += add;
    __syncthreads();
  }
  if (t < n_chunks) partials[t] = s[t] - v;
}

__global__ __launch_bounds__(256) void scan3_kernel(
    int* __restrict__ offs, const int* __restrict__ partials, int n_nodes) {
  const int i = blockIdx.x * 256 + threadIdx.x;
  if (i < n_nodes) offs[i] += partials[i >> 10];
}

__global__ __launch_bounds__(256) void reorder_kernel(
    const int* __restrict__ src, const int* __restrict__ dst,
    const int* __restrict__ rel, const float* __restrict__ norm,
    const int* __restrict__ offs, int* __restrict__ cursor,
    int2* __restrict__ edgebuf, int n_edges) {
  const int e = blockIdx.x * 256 + threadIdx.x;
  if (e >= n_edges) return;
  const int d = dst[e];
  const int pos = offs[d] + atomicAdd(&cursor[d], 1);
  edgebuf[pos] = make_int2(src[e] | (rel[e] << 27), __float_as_int(norm[e]));
}

// ---------------- fused gather + skip + relu ----------------
// 16 threads per node; each handles one float4 chunk of the 64-wide feature.
__global__ __launch_bounds__(256) void gather_kernel(
    const float* __restrict__ hr, const int2* __restrict__ edgebuf,
    const int* __restrict__ offs, const int* __restrict__ deg,
    const float* __restrict__ skip, float* __restrict__ out,
    int n_nodes) {
  const long gid = (long)blockIdx.x * 256 + threadIdx.x;
  const int n = (int)(gid >> 4);
  if (n >= n_nodes) return;
  const int c = (int)(gid & 15) * 4;

  const int beg = offs[n];
  const int cnt = deg[n];

  float4 acc0 = {0.f, 0.f, 0.f, 0.f};
  float4 acc1 = {0.f, 0.f, 0.f, 0.f};
  int i = 0;
  for (; i + 1 < cnt; i += 2) {
    const int2 ea = edgebuf[beg + i];
    const int2 eb = edgebuf[beg + i + 1];
    const int sa = ea.x & SRC_MASK;
    const int ra = ((unsigned)ea.x) >> 27;
    const int sb = eb.x & SRC_MASK;
    const int rb = ((unsigned)eb.x) >> 27;
    const float na = __int_as_float(ea.y);
    const float nb = __int_as_float(eb.y);
    const float4 va = *reinterpret_cast<const float4*>(
        &hr[((long)ra * n_nodes + sa) * 64 + c]);
    const float4 vb = *reinterpret_cast<const float4*>(
        &hr[((long)rb * n_nodes + sb) * 64 + c]);
    acc0.x += va.x * na; acc0.y += va.y * na; acc0.z += va.z * na; acc0.w += va.w * na;
    acc1.x += vb.x * nb; acc1.y += vb.y * nb; acc1.z += vb.z * nb; acc1.w += vb.w * nb;
  }
  if (i < cnt) {
    const int2 ea = edgebuf[beg + i];
    const int sa = ea.x & SRC_MASK;
    const int ra = ((unsigned)ea.x) >> 27;
    const float na = __int_as_float(ea.y);
    const float4 va = *reinterpret_cast<const float4*>(
        &hr[((long)ra * n_nodes + sa) * 64 + c]);
    acc0.x += va.x * na; acc0.y += va.y * na; acc0.z += va.z * na; acc0.w += va.w * na;
  }
  float4 a;
  a.x = acc0.x + acc1.x; a.y = acc0.y + acc1.y;
  a.z = acc0.z + acc1.z; a.w = acc0.w + acc1.w;
  if (skip != nullptr) {
    const float4 s = *reinterpret_cast<const float4*>(&skip[(long)n * 64 + c]);
    a.x += s.x; a.y += s.y; a.z += s.z; a.w += s.w;
  }
  a.x = fmaxf(a.x, 0.f); a.y = fmaxf(a.y, 0.f);
  a.z = fmaxf(a.z, 0.f); a.w = fmaxf(a.w, 0.f);
  *reinterpret_cast<float4*>(&out[(long)n * 64 + c]) = a;
}

// xa = x@Wa.T + ba -> out[0 : N*2], xb = x@Wb.T + bb -> out[N*2 : N*2+N*21]
__global__ __launch_bounds__(256) void heads_kernel(
    const float* __restrict__ x, const float* __restrict__ Wa,
    const float* __restrict__ ba, const float* __restrict__ Wb,
    const float* __restrict__ bb, float* __restrict__ out, int n_nodes) {
  __shared__ float xs[64][65];
  __shared__ float wl[23][64];
  __shared__ float bl[23];
  const int tid = threadIdx.x;
  const int base = blockIdx.x * 64;

  for (int idx = tid; idx < 2 * 64; idx += 256) wl[idx >> 6][idx & 63] = Wa[idx];
  for (int idx = tid; idx < 21 * 64; idx += 256) wl[2 + (idx >> 6)][idx & 63] = Wb[idx];
  if (tid < 2) bl[tid] = ba[tid];
  else if (tid < 23) bl[tid] = bb[tid - 2];
  const int nrows = min(64, n_nodes - base);
  for (int idx = tid; idx < nrows * 64; idx += 256)
    xs[idx >> 6][idx & 63] = x[(long)base * 64 + idx];
  __syncthreads();

  for (int idx = tid; idx < nrows * 23; idx += 256) {
    const int n = idx / 23;
    const int s = idx % 23;
    float acc = 0.f;
#pragma unroll
    for (int k = 0; k < 64; ++k) acc += xs[n][k] * wl[s][k];
    acc += bl[s];
    const long node = base + n;
    if (s < 2) out[node * 2 + s] = acc;
    else out[(long)n_nodes * 2 + node * 21 + (s - 2)] = acc;
  }
}

extern "C" void kernel_launch(void* const* d_in, const int* in_sizes, int n_in,
                              void* d_out, int out_size, void* d_ws, size_t ws_size,
                              hipStream_t stream) {
  const float* v    = (const float*)d_in[0];
  const int*   esrc = (const int*)d_in[1];
  const int*   edst = (const int*)d_in[2];
  const int*   erel = (const int*)d_in[3];
  const float* norm = (const float*)d_in[4];
  const float* W1   = (const float*)d_in[5];
  const float* W2   = (const float*)d_in[6];
  const float* W3   = (const float*)d_in[7];
  const float* Wa   = (const float*)d_in[8];
  const float* ba   = (const float*)d_in[9];
  const float* Wb   = (const float*)d_in[10];
  const float* bb   = (const float*)d_in[11];

  const int nN = in_sizes[0] / D;   // 100000
  const int E  = in_sizes[1];       // 1200000

  // ---- workspace layout
  float* hr      = (float*)d_ws;                   // [3][nN][64]
  float* bufA    = hr + 3L * nN * D;               // [nN][64]
  float* bufB    = bufA + (long)nN * D;            // [nN][64]
  int*   deg     = (int*)(bufB + (long)nN * D);    // [nN]
  int*   offs    = deg + nN;                       // [nN]
  int*   cursor  = offs + nN;                      // [nN]
  int*   partials= cursor + nN;                    // [256]
  int2*  edgebuf = (int2*)(partials + 256);        // [E]

  const int eblocks  = (E + 255) / 256;
  const int tblocks  = (nN + 63) / 64;
  const int gblocks  = (int)(((long)nN * 16 + 255) / 256);
  const int nchunks  = (nN + 1023) / 1024;

  // ---- CSR build (once per call)
  hipMemsetAsync(deg, 0, (size_t)nN * sizeof(int), stream);
  hipMemsetAsync(cursor, 0, (size_t)nN * sizeof(int), stream);
  hist_kernel<<<eblocks, 256, 0, stream>>>(edst, deg, E);
  scan1_kernel<<<nchunks, 256, 0, stream>>>(deg, offs, partials, nN);
  scan2_kernel<<<1, 256, 0, stream>>>(partials, nchunks);
  scan3_kernel<<<(nN + 255) / 256, 256, 0, stream>>>(offs, partials, nN);
  reorder_kernel<<<eblocks, 256, 0, stream>>>(esrc, edst, erel, norm, offs, cursor,
                                              edgebuf, E);

  // ---- layer 1: v -> bufA (no skip)
  transform_kernel<<<tblocks, 256, 0, stream>>>(v, W1, hr, nN);
  gather_kernel<<<gblocks, 256, 0, stream>>>(hr, edgebuf, offs, deg, nullptr, bufA, nN);

  // ---- layer 2: bufA -> bufB (skip)
  transform_kernel<<<tblocks, 256, 0, stream>>>(bufA, W2, hr, nN);
  gather_kernel<<<gblocks, 256, 0, stream>>>(hr, edgebuf, offs, deg, bufA, bufB, nN);

  // ---- layer 3: bufB -> bufA (skip)
  transform_kernel<<<tblocks, 256, 0, stream>>>(bufB, W3, hr, nN);
  gather_kernel<<<gblocks, 256, 0, stream>>>(hr, edgebuf, offs, deg, bufB, bufA, nN);

  // ---- heads
  heads_kernel<<<tblocks, 256, 0, stream>>>(bufA, Wa, ba, Wb, bb, (float*)d_out, nN);
}